// Round 1
// baseline (6348.903 us; speedup 1.0000x reference)
//
#include <hip/hip_runtime.h>

// ---------------------------------------------------------------------------
// PointNet mesh GNN, fp32.
// Edges: for each face (f0,f1,f2), directed pairs (src,dst):
//   (0,1),(0,2),(1,2),(1,0),(2,0),(2,1)
// layer: x = [h[src], posn[src]-posn[dst]] ; m = relu(x@Wa+ba)@Wb+bb
//        h_out[dst] = max(0, max over incoming m)   (0-init + atomicMax on bits)
// ---------------------------------------------------------------------------

__global__ __launch_bounds__(256) void prep_kernel(
    const float* __restrict__ pos, float* __restrict__ posn, int N,
    const float* __restrict__ W1a, const float* __restrict__ W2a,
    const float* __restrict__ W3a,
    float* __restrict__ W1aT, float* __restrict__ W2aT, float* __restrict__ W3aT)
{
    int idx = blockIdx.x * blockDim.x + threadIdx.x;
    if (idx < N) {
        float x = pos[idx * 3 + 0];
        float y = pos[idx * 3 + 1];
        float z = pos[idx * 3 + 2];
        float s = fmaxf(fabsf(x) + fabsf(y) + fabsf(z), 1e-12f);
        float inv = 1.0f / s;
        posn[idx * 3 + 0] = x * inv;
        posn[idx * 3 + 1] = y * inv;
        posn[idx * 3 + 2] = z * inv;
    }
    if (blockIdx.x == 0) {
        // transpose Wa matrices: WaT[k*IN + i] = Wa[i*OUT + k]
        for (int t = threadIdx.x; t < 6 * 32; t += blockDim.x) {
            int i = t / 32, k = t % 32;
            W1aT[k * 6 + i] = W1a[t];
        }
        for (int t = threadIdx.x; t < 35 * 32; t += blockDim.x) {
            int i = t / 32, k = t % 32;
            W2aT[k * 35 + i] = W2a[t];
        }
        for (int t = threadIdx.x; t < 35 * 64; t += blockDim.x) {
            int i = t / 64, k = t % 64;
            W3aT[k * 35 + i] = W3a[t];
        }
    }
}

// One thread per directed edge. INH = input feature count (h), IN = INH+3.
// WaT is transposed: WaT[k*IN + i]. Wb row-major [OUT][OUT] i.e. Wb[k*OUT+o].
template <int INH, int OUT>
__global__ __launch_bounds__(256) void layer_kernel(
    const float* __restrict__ h, const float* __restrict__ posn,
    const int* __restrict__ face, int F,
    const float* __restrict__ WaT, const float* __restrict__ ba,
    const float* __restrict__ Wb, const float* __restrict__ bb,
    float* __restrict__ hout)
{
    constexpr int IN = INH + 3;
    int e = blockIdx.x * blockDim.x + threadIdx.x;
    int tot = 6 * F;
    if (e >= tot) return;
    int et = e / F;          // 0..5 edge type; consecutive threads share et
    int f  = e - et * F;
    int srcRow = et >> 1;
    int dstRow = (srcRow + 1 + (et & 1)) % 3;
    int src = face[srcRow * F + f];
    int dst = face[dstRow * F + f];

    float x[IN];
    if constexpr (INH % 4 == 0) {
        const float4* hp = (const float4*)(h + (size_t)src * INH);
        #pragma unroll
        for (int i4 = 0; i4 < INH / 4; i4++) {
            float4 v = hp[i4];
            x[i4 * 4 + 0] = v.x;
            x[i4 * 4 + 1] = v.y;
            x[i4 * 4 + 2] = v.z;
            x[i4 * 4 + 3] = v.w;
        }
    } else {
        #pragma unroll
        for (int i = 0; i < INH; i++) x[i] = h[(size_t)src * INH + i];
    }
    #pragma unroll
    for (int c = 0; c < 3; c++)
        x[INH + c] = posn[src * 3 + c] - posn[dst * 3 + c];

    float acc[OUT];
    #pragma unroll
    for (int o = 0; o < OUT; o++) acc[o] = bb[o];

    for (int k = 0; k < OUT; k++) {
        float hk = ba[k];
        #pragma unroll
        for (int i = 0; i < IN; i++)
            hk = fmaf(x[i], WaT[k * IN + i], hk);
        hk = fmaxf(hk, 0.0f);
        #pragma unroll
        for (int o = 0; o < OUT; o++)
            acc[o] = fmaf(hk, Wb[k * OUT + o], acc[o]);
    }

    float* outp = hout + (size_t)dst * OUT;
    #pragma unroll
    for (int o = 0; o < OUT; o++) {
        float m = fmaxf(acc[o], 0.0f);
        atomicMax((int*)(outp + o), __float_as_int(m));
    }
}

// Global max pool: batch is sorted; block handles 1024 nodes; thread owns
// feature (tid & 63), strides nodes by 4; flush running max at batch change.
__global__ __launch_bounds__(256) void pool_kernel(
    const float* __restrict__ h3, const int* __restrict__ batch, int N,
    float* __restrict__ g)
{
    int o = threadIdx.x & 63;
    int sub = threadIdx.x >> 6;
    int n0 = blockIdx.x * 1024;
    int nend = min(n0 + 1024, N);
    int cur = -1;
    float run = 0.0f;
    for (int n = n0 + sub; n < nend; n += 4) {
        int b = batch[n];
        if (b != cur) {
            if (cur >= 0) atomicMax((int*)&g[cur * 64 + o], __float_as_int(run));
            cur = b;
            run = 0.0f;
        }
        run = fmaxf(run, h3[(size_t)n * 64 + o]);
    }
    if (cur >= 0) atomicMax((int*)&g[cur * 64 + o], __float_as_int(run));
}

__global__ __launch_bounds__(256) void head_kernel(
    const float* __restrict__ g, const float* __restrict__ Wc,
    const float* __restrict__ bc, float* __restrict__ out)
{
    int idx = blockIdx.x * blockDim.x + threadIdx.x;
    if (idx >= 64 * 41) return;
    int bg = idx / 41;
    int o = idx - bg * 41;
    float acc = bc[o];
    #pragma unroll 8
    for (int k = 0; k < 64; k++)
        acc = fmaf(g[bg * 64 + k], Wc[k * 41 + o], acc);
    out[idx] = acc;
}

extern "C" void kernel_launch(void* const* d_in, const int* in_sizes, int n_in,
                              void* d_out, int out_size, void* d_ws, size_t ws_size,
                              hipStream_t stream)
{
    const float* pos   = (const float*)d_in[0];
    const int*   batch = (const int*)d_in[1];
    const int*   face  = (const int*)d_in[2];
    const float* W1a = (const float*)d_in[3];
    const float* b1a = (const float*)d_in[4];
    const float* W1b = (const float*)d_in[5];
    const float* b1b = (const float*)d_in[6];
    const float* W2a = (const float*)d_in[7];
    const float* b2a = (const float*)d_in[8];
    const float* W2b = (const float*)d_in[9];
    const float* b2b = (const float*)d_in[10];
    const float* W3a = (const float*)d_in[11];
    const float* b3a = (const float*)d_in[12];
    const float* W3b = (const float*)d_in[13];
    const float* b3b = (const float*)d_in[14];
    const float* Wc  = (const float*)d_in[15];
    const float* bc  = (const float*)d_in[16];

    int N = in_sizes[0] / 3;
    int F = in_sizes[2] / 3;
    int E = 6 * F;

    float* ws   = (float*)d_ws;
    float* posn = ws;
    float* W1aT = posn + (size_t)N * 3;
    float* W2aT = W1aT + 6 * 32;
    float* W3aT = W2aT + 35 * 32;
    float* h1   = W3aT + 35 * 64;
    float* h2   = h1 + (size_t)N * 32;
    float* h3   = h2 + (size_t)N * 32;
    float* g    = h3 + (size_t)N * 64;

    // zero h1, h2, h3, g (contiguous)
    size_t zero_bytes = ((size_t)N * 128 + 64 * 64) * sizeof(float);
    hipMemsetAsync(h1, 0, zero_bytes, stream);

    prep_kernel<<<(N + 255) / 256, 256, 0, stream>>>(
        pos, posn, N, W1a, W2a, W3a, W1aT, W2aT, W3aT);

    dim3 blk(256);
    dim3 grd((E + 255) / 256);
    layer_kernel<3, 32><<<grd, blk, 0, stream>>>(
        posn, posn, face, F, W1aT, b1a, W1b, b1b, h1);
    layer_kernel<32, 32><<<grd, blk, 0, stream>>>(
        h1, posn, face, F, W2aT, b2a, W2b, b2b, h2);
    layer_kernel<32, 64><<<grd, blk, 0, stream>>>(
        h2, posn, face, F, W3aT, b3a, W3b, b3b, h3);

    pool_kernel<<<(N + 1023) / 1024, 256, 0, stream>>>(h3, batch, N, g);
    head_kernel<<<(64 * 41 + 255) / 256, 256, 0, stream>>>(g, Wc, bc, (float*)d_out);
}

// Round 2
// 1999.868 us; speedup vs baseline: 3.1747x; 3.1747x over previous
//
#include <hip/hip_runtime.h>

// ---------------------------------------------------------------------------
// PointNet mesh GNN, fp32 — gather formulation (no atomics in hot path).
// For each face (f0,f1,f2): vertex r receives messages from the other two.
// CSR of incoming srcs per node; one thread per node computes all incoming
// messages in registers, maxes, writes its output row once.
// ---------------------------------------------------------------------------

__global__ __launch_bounds__(256) void prep_kernel(
    const float* __restrict__ pos, float* __restrict__ posn, int N,
    const float* __restrict__ W1a, const float* __restrict__ W2a,
    const float* __restrict__ W3a,
    float* __restrict__ W1aT, float* __restrict__ W2aT, float* __restrict__ W3aT)
{
    int idx = blockIdx.x * blockDim.x + threadIdx.x;
    if (idx < N) {
        float x = pos[idx * 3 + 0];
        float y = pos[idx * 3 + 1];
        float z = pos[idx * 3 + 2];
        float s = fmaxf(fabsf(x) + fabsf(y) + fabsf(z), 1e-12f);
        float inv = 1.0f / s;
        posn[idx * 3 + 0] = x * inv;
        posn[idx * 3 + 1] = y * inv;
        posn[idx * 3 + 2] = z * inv;
    }
    if (blockIdx.x == 0) {
        for (int t = threadIdx.x; t < 6 * 32; t += blockDim.x) {
            int i = t / 32, k = t % 32;
            W1aT[k * 6 + i] = W1a[t];
        }
        for (int t = threadIdx.x; t < 35 * 32; t += blockDim.x) {
            int i = t / 32, k = t % 32;
            W2aT[k * 35 + i] = W2a[t];
        }
        for (int t = threadIdx.x; t < 35 * 64; t += blockDim.x) {
            int i = t / 64, k = t % 64;
            W3aT[k * 35 + i] = W3a[t];
        }
    }
}

// deg[v] += 2 for each (face, slot) occurrence of v
__global__ __launch_bounds__(256) void count_kernel(
    const int* __restrict__ face, int F3, int* __restrict__ deg)
{
    int t = blockIdx.x * blockDim.x + threadIdx.x;
    if (t < F3) atomicAdd(&deg[face[t]], 2);
}

// Single-block serial-chunk exclusive scan: indptr[i] = prefix; degcur[i]
// becomes the fill cursor (in-place). indptr[N] = total.
__global__ __launch_bounds__(1024) void scan_kernel(
    int* __restrict__ degcur, int* __restrict__ indptr, int N)
{
    __shared__ int part[1024];
    int tid = threadIdx.x;
    int per = (N + 1023) / 1024;
    int s0 = tid * per, s1 = min(s0 + per, N);
    int sum = 0;
    for (int i = s0; i < s1; i++) sum += degcur[i];
    part[tid] = sum;
    __syncthreads();
    for (int off = 1; off < 1024; off <<= 1) {
        int t = (tid >= off) ? part[tid - off] : 0;
        __syncthreads();
        part[tid] += t;
        __syncthreads();
    }
    int run = part[tid] - sum;  // exclusive prefix
    for (int i = s0; i < s1; i++) {
        int d = degcur[i];
        indptr[i] = run;
        degcur[i] = run;  // cursor for fill
        run += d;
    }
    if (tid == 1023) indptr[N] = part[1023];
}

// For each (face, slot r): node face[r] receives from face[r+1], face[r+2]
__global__ __launch_bounds__(256) void fill_kernel(
    const int* __restrict__ face, int F, int* __restrict__ cursor,
    int* __restrict__ srcids)
{
    int t = blockIdx.x * blockDim.x + threadIdx.x;
    if (t >= 3 * F) return;
    int r = t / F;
    int f = t - r * F;
    int v = face[t];
    int r1 = r + 1; if (r1 == 3) r1 = 0;
    int r2 = r + 2; if (r2 >= 3) r2 -= 3;
    int a = face[r1 * F + f];
    int b = face[r2 * F + f];
    int base = atomicAdd(&cursor[v], 2);
    srcids[base] = a;
    srcids[base + 1] = b;
}

// One thread per node: loop incoming edges, compute message MLP in registers,
// running max (init 0 == fused downstream ReLU + empty-segment fill).
template <int INH, int OUT>
__global__ __launch_bounds__(128) void layer_node_kernel(
    const float* __restrict__ h, const float* __restrict__ posn,
    const int* __restrict__ indptr, const int* __restrict__ srcids,
    const float* __restrict__ WaT, const float* __restrict__ ba,
    const float* __restrict__ Wb, const float* __restrict__ bb,
    float* __restrict__ hout, int N)
{
    constexpr int IN = INH + 3;
    int n = blockIdx.x * blockDim.x + threadIdx.x;
    if (n >= N) return;
    float px = posn[n * 3 + 0];
    float py = posn[n * 3 + 1];
    float pz = posn[n * 3 + 2];
    int e0 = indptr[n], e1 = indptr[n + 1];

    float hmax[OUT];
    #pragma unroll
    for (int o = 0; o < OUT; o++) hmax[o] = 0.0f;

    for (int e = e0; e < e1; e++) {
        int src = srcids[e];
        float x[IN];
        if constexpr (INH % 4 == 0) {
            const float4* hp = (const float4*)(h + (size_t)src * INH);
            #pragma unroll
            for (int i4 = 0; i4 < INH / 4; i4++) {
                float4 v = hp[i4];
                x[i4 * 4 + 0] = v.x;
                x[i4 * 4 + 1] = v.y;
                x[i4 * 4 + 2] = v.z;
                x[i4 * 4 + 3] = v.w;
            }
        } else {
            #pragma unroll
            for (int i = 0; i < INH; i++) x[i] = h[(size_t)src * INH + i];
        }
        x[INH + 0] = posn[src * 3 + 0] - px;
        x[INH + 1] = posn[src * 3 + 1] - py;
        x[INH + 2] = posn[src * 3 + 2] - pz;

        float acc[OUT];
        #pragma unroll
        for (int o = 0; o < OUT; o++) acc[o] = bb[o];

        #pragma unroll 2
        for (int k = 0; k < OUT; k++) {
            float hk = ba[k];
            #pragma unroll
            for (int i = 0; i < IN; i++)
                hk = fmaf(x[i], WaT[k * IN + i], hk);
            hk = fmaxf(hk, 0.0f);
            #pragma unroll
            for (int o = 0; o < OUT; o++)
                acc[o] = fmaf(hk, Wb[k * OUT + o], acc[o]);
        }
        #pragma unroll
        for (int o = 0; o < OUT; o++) hmax[o] = fmaxf(hmax[o], acc[o]);
    }

    float* outp = hout + (size_t)n * OUT;
    #pragma unroll
    for (int o4 = 0; o4 < OUT / 4; o4++) {
        float4 v;
        v.x = hmax[o4 * 4 + 0];
        v.y = hmax[o4 * 4 + 1];
        v.z = hmax[o4 * 4 + 2];
        v.w = hmax[o4 * 4 + 3];
        ((float4*)outp)[o4] = v;
    }
}

// Global max pool over sorted batch ids (h3 >= 0, init 0).
__global__ __launch_bounds__(256) void pool_kernel(
    const float* __restrict__ h3, const int* __restrict__ batch, int N,
    float* __restrict__ g)
{
    int o = threadIdx.x & 63;
    int sub = threadIdx.x >> 6;
    int n0 = blockIdx.x * 1024;
    int nend = min(n0 + 1024, N);
    int cur = -1;
    float run = 0.0f;
    for (int n = n0 + sub; n < nend; n += 4) {
        int b = batch[n];
        if (b != cur) {
            if (cur >= 0) atomicMax((int*)&g[cur * 64 + o], __float_as_int(run));
            cur = b;
            run = 0.0f;
        }
        run = fmaxf(run, h3[(size_t)n * 64 + o]);
    }
    if (cur >= 0) atomicMax((int*)&g[cur * 64 + o], __float_as_int(run));
}

__global__ __launch_bounds__(256) void head_kernel(
    const float* __restrict__ g, const float* __restrict__ Wc,
    const float* __restrict__ bc, float* __restrict__ out)
{
    int idx = blockIdx.x * blockDim.x + threadIdx.x;
    if (idx >= 64 * 41) return;
    int bg = idx / 41;
    int o = idx - bg * 41;
    float acc = bc[o];
    #pragma unroll 8
    for (int k = 0; k < 64; k++)
        acc = fmaf(g[bg * 64 + k], Wc[k * 41 + o], acc);
    out[idx] = acc;
}

extern "C" void kernel_launch(void* const* d_in, const int* in_sizes, int n_in,
                              void* d_out, int out_size, void* d_ws, size_t ws_size,
                              hipStream_t stream)
{
    const float* pos   = (const float*)d_in[0];
    const int*   batch = (const int*)d_in[1];
    const int*   face  = (const int*)d_in[2];
    const float* W1a = (const float*)d_in[3];
    const float* b1a = (const float*)d_in[4];
    const float* W1b = (const float*)d_in[5];
    const float* b1b = (const float*)d_in[6];
    const float* W2a = (const float*)d_in[7];
    const float* b2a = (const float*)d_in[8];
    const float* W2b = (const float*)d_in[9];
    const float* b2b = (const float*)d_in[10];
    const float* W3a = (const float*)d_in[11];
    const float* b3a = (const float*)d_in[12];
    const float* W3b = (const float*)d_in[13];
    const float* b3b = (const float*)d_in[14];
    const float* Wc  = (const float*)d_in[15];
    const float* bc  = (const float*)d_in[16];

    int N = in_sizes[0] / 3;
    int F = in_sizes[2] / 3;
    int E = 6 * F;

    float* ws   = (float*)d_ws;
    float* posn = ws;
    float* W1aT = posn + (size_t)N * 3;
    float* W2aT = W1aT + 6 * 32;
    float* W3aT = W2aT + 35 * 32;
    float* h1   = W3aT + 35 * 64;
    float* h2   = h1 + (size_t)N * 32;
    float* h3   = h2 + (size_t)N * 32;
    float* g    = h3 + (size_t)N * 64;
    int* deg    = (int*)(g + 64 * 64);       // doubles as fill cursor
    int* indptr = deg + N;
    int* srcids = indptr + (N + 1);

    hipMemsetAsync(deg, 0, (size_t)N * sizeof(int), stream);
    hipMemsetAsync(g, 0, 64 * 64 * sizeof(float), stream);

    prep_kernel<<<(N + 255) / 256, 256, 0, stream>>>(
        pos, posn, N, W1a, W2a, W3a, W1aT, W2aT, W3aT);

    int F3 = 3 * F;
    count_kernel<<<(F3 + 255) / 256, 256, 0, stream>>>(face, F3, deg);
    scan_kernel<<<1, 1024, 0, stream>>>(deg, indptr, N);
    fill_kernel<<<(F3 + 255) / 256, 256, 0, stream>>>(face, F, deg, srcids);

    dim3 blk(128);
    dim3 grd((N + 127) / 128);
    layer_node_kernel<3, 32><<<grd, blk, 0, stream>>>(
        posn, posn, indptr, srcids, W1aT, b1a, W1b, b1b, h1, N);
    layer_node_kernel<32, 32><<<grd, blk, 0, stream>>>(
        h1, posn, indptr, srcids, W2aT, b2a, W2b, b2b, h2, N);
    layer_node_kernel<32, 64><<<grd, blk, 0, stream>>>(
        h2, posn, indptr, srcids, W3aT, b3a, W3b, b3b, h3, N);

    pool_kernel<<<(N + 1023) / 1024, 256, 0, stream>>>(h3, batch, N, g);
    head_kernel<<<(64 * 41 + 255) / 256, 256, 0, stream>>>(g, Wc, bc, (float*)d_out);
}

// Round 3
// 1802.507 us; speedup vs baseline: 3.5223x; 1.1095x over previous
//
#include <hip/hip_runtime.h>

// ---------------------------------------------------------------------------
// PointNet mesh GNN, fp32 — gather formulation, SPLIT threads per node.
// For each face (f0,f1,f2): vertex r receives messages from the other two.
// CSR of incoming srcs per node; SPLIT=4 threads cooperate per node (strided
// edges, full fused MLP per edge, shfl-butterfly max, split coalesced write).
// ---------------------------------------------------------------------------

__global__ __launch_bounds__(256) void prep_kernel(
    const float* __restrict__ pos, float* __restrict__ posn, int N,
    const float* __restrict__ W1a, const float* __restrict__ W2a,
    const float* __restrict__ W3a,
    float* __restrict__ W1aT, float* __restrict__ W2aT, float* __restrict__ W3aT)
{
    int idx = blockIdx.x * blockDim.x + threadIdx.x;
    if (idx < N) {
        float x = pos[idx * 3 + 0];
        float y = pos[idx * 3 + 1];
        float z = pos[idx * 3 + 2];
        float s = fmaxf(fabsf(x) + fabsf(y) + fabsf(z), 1e-12f);
        float inv = 1.0f / s;
        posn[idx * 3 + 0] = x * inv;
        posn[idx * 3 + 1] = y * inv;
        posn[idx * 3 + 2] = z * inv;
    }
    if (blockIdx.x == 0) {
        for (int t = threadIdx.x; t < 6 * 32; t += blockDim.x) {
            int i = t / 32, k = t % 32;
            W1aT[k * 6 + i] = W1a[t];
        }
        for (int t = threadIdx.x; t < 35 * 32; t += blockDim.x) {
            int i = t / 32, k = t % 32;
            W2aT[k * 35 + i] = W2a[t];
        }
        for (int t = threadIdx.x; t < 35 * 64; t += blockDim.x) {
            int i = t / 64, k = t % 64;
            W3aT[k * 35 + i] = W3a[t];
        }
    }
}

// deg[v] += 2 for each (face, slot) occurrence of v
__global__ __launch_bounds__(256) void count_kernel(
    const int* __restrict__ face, int F3, int* __restrict__ deg)
{
    int t = blockIdx.x * blockDim.x + threadIdx.x;
    if (t < F3) atomicAdd(&deg[face[t]], 2);
}

// Single-block serial-chunk exclusive scan: indptr[i] = prefix; degcur[i]
// becomes the fill cursor (in-place). indptr[N] = total.
__global__ __launch_bounds__(1024) void scan_kernel(
    int* __restrict__ degcur, int* __restrict__ indptr, int N)
{
    __shared__ int part[1024];
    int tid = threadIdx.x;
    int per = (N + 1023) / 1024;
    int s0 = tid * per, s1 = min(s0 + per, N);
    int sum = 0;
    for (int i = s0; i < s1; i++) sum += degcur[i];
    part[tid] = sum;
    __syncthreads();
    for (int off = 1; off < 1024; off <<= 1) {
        int t = (tid >= off) ? part[tid - off] : 0;
        __syncthreads();
        part[tid] += t;
        __syncthreads();
    }
    int run = part[tid] - sum;  // exclusive prefix
    for (int i = s0; i < s1; i++) {
        int d = degcur[i];
        indptr[i] = run;
        degcur[i] = run;  // cursor for fill
        run += d;
    }
    if (tid == 1023) indptr[N] = part[1023];
}

// For each (face, slot r): node face[r] receives from face[r+1], face[r+2]
__global__ __launch_bounds__(256) void fill_kernel(
    const int* __restrict__ face, int F, int* __restrict__ cursor,
    int* __restrict__ srcids)
{
    int t = blockIdx.x * blockDim.x + threadIdx.x;
    if (t >= 3 * F) return;
    int r = t / F;
    int f = t - r * F;
    int v = face[t];
    int r1 = r + 1; if (r1 == 3) r1 = 0;
    int r2 = r + 2; if (r2 >= 3) r2 -= 3;
    int a = face[r1 * F + f];
    int b = face[r2 * F + f];
    int base = atomicAdd(&cursor[v], 2);
    srcids[base] = a;
    srcids[base + 1] = b;
}

// SPLIT threads per node: thread t handles edges e0+t, e0+t+SPLIT, ...
// Full fused message MLP per edge in registers; butterfly max across the
// SPLIT lanes; each lane writes its OUT/SPLIT chunk of the output row.
// Running max inits at 0 == fused downstream ReLU + empty-segment fill.
template <int INH, int OUT, int SPLIT, int MINW>
__global__ __launch_bounds__(256, MINW) void layer_node_kernel(
    const float* __restrict__ h, const float* __restrict__ posn,
    const int* __restrict__ indptr, const int* __restrict__ srcids,
    const float* __restrict__ WaT, const float* __restrict__ ba,
    const float* __restrict__ Wb, const float* __restrict__ bb,
    float* __restrict__ hout, int N)
{
    constexpr int IN = INH + 3;
    int gt = blockIdx.x * blockDim.x + threadIdx.x;
    int n = gt >> 2;              // SPLIT == 4
    int t = gt & 3;
    static_assert(SPLIT == 4, "lane math assumes SPLIT=4");
    if (n >= N) return;
    float px = posn[n * 3 + 0];
    float py = posn[n * 3 + 1];
    float pz = posn[n * 3 + 2];
    int e0 = indptr[n], e1 = indptr[n + 1];

    float hmax[OUT];
    #pragma unroll
    for (int o = 0; o < OUT; o++) hmax[o] = 0.0f;

    for (int e = e0 + t; e < e1; e += SPLIT) {
        int src = srcids[e];
        float x[IN];
        if constexpr (INH % 4 == 0) {
            const float4* hp = (const float4*)(h + (size_t)src * INH);
            #pragma unroll
            for (int i4 = 0; i4 < INH / 4; i4++) {
                float4 v = hp[i4];
                x[i4 * 4 + 0] = v.x;
                x[i4 * 4 + 1] = v.y;
                x[i4 * 4 + 2] = v.z;
                x[i4 * 4 + 3] = v.w;
            }
        } else {
            #pragma unroll
            for (int i = 0; i < INH; i++) x[i] = h[(size_t)src * INH + i];
        }
        x[INH + 0] = posn[src * 3 + 0] - px;
        x[INH + 1] = posn[src * 3 + 1] - py;
        x[INH + 2] = posn[src * 3 + 2] - pz;

        float acc[OUT];
        #pragma unroll
        for (int o = 0; o < OUT; o++) acc[o] = bb[o];

        #pragma unroll 2
        for (int k = 0; k < OUT; k++) {
            float hk = ba[k];
            #pragma unroll
            for (int i = 0; i < IN; i++)
                hk = fmaf(x[i], WaT[k * IN + i], hk);
            hk = fmaxf(hk, 0.0f);
            #pragma unroll
            for (int o = 0; o < OUT; o++)
                acc[o] = fmaf(hk, Wb[k * OUT + o], acc[o]);
        }
        #pragma unroll
        for (int o = 0; o < OUT; o++) hmax[o] = fmaxf(hmax[o], acc[o]);
    }

    // butterfly max across the 4 cooperating lanes (consecutive, wave-aligned)
    #pragma unroll
    for (int m = 1; m < SPLIT; m <<= 1) {
        #pragma unroll
        for (int o = 0; o < OUT; o++)
            hmax[o] = fmaxf(hmax[o], __shfl_xor(hmax[o], m));
    }

    // each lane writes its quarter of the row
    constexpr int CH = OUT / SPLIT;
    float* outp = hout + (size_t)n * OUT + t * CH;
    #pragma unroll
    for (int o4 = 0; o4 < CH / 4; o4++) {
        float4 v;
        v.x = hmax[t * CH + o4 * 4 + 0];
        v.y = hmax[t * CH + o4 * 4 + 1];
        v.z = hmax[t * CH + o4 * 4 + 2];
        v.w = hmax[t * CH + o4 * 4 + 3];
        ((float4*)outp)[o4] = v;
    }
}

// Global max pool over sorted batch ids (h3 >= 0, init 0).
__global__ __launch_bounds__(256) void pool_kernel(
    const float* __restrict__ h3, const int* __restrict__ batch, int N,
    float* __restrict__ g)
{
    int o = threadIdx.x & 63;
    int sub = threadIdx.x >> 6;
    int n0 = blockIdx.x * 1024;
    int nend = min(n0 + 1024, N);
    int cur = -1;
    float run = 0.0f;
    for (int n = n0 + sub; n < nend; n += 4) {
        int b = batch[n];
        if (b != cur) {
            if (cur >= 0) atomicMax((int*)&g[cur * 64 + o], __float_as_int(run));
            cur = b;
            run = 0.0f;
        }
        run = fmaxf(run, h3[(size_t)n * 64 + o]);
    }
    if (cur >= 0) atomicMax((int*)&g[cur * 64 + o], __float_as_int(run));
}

__global__ __launch_bounds__(256) void head_kernel(
    const float* __restrict__ g, const float* __restrict__ Wc,
    const float* __restrict__ bc, float* __restrict__ out)
{
    int idx = blockIdx.x * blockDim.x + threadIdx.x;
    if (idx >= 64 * 41) return;
    int bg = idx / 41;
    int o = idx - bg * 41;
    float acc = bc[o];
    #pragma unroll 8
    for (int k = 0; k < 64; k++)
        acc = fmaf(g[bg * 64 + k], Wc[k * 41 + o], acc);
    out[idx] = acc;
}

extern "C" void kernel_launch(void* const* d_in, const int* in_sizes, int n_in,
                              void* d_out, int out_size, void* d_ws, size_t ws_size,
                              hipStream_t stream)
{
    const float* pos   = (const float*)d_in[0];
    const int*   batch = (const int*)d_in[1];
    const int*   face  = (const int*)d_in[2];
    const float* W1a = (const float*)d_in[3];
    const float* b1a = (const float*)d_in[4];
    const float* W1b = (const float*)d_in[5];
    const float* b1b = (const float*)d_in[6];
    const float* W2a = (const float*)d_in[7];
    const float* b2a = (const float*)d_in[8];
    const float* W2b = (const float*)d_in[9];
    const float* b2b = (const float*)d_in[10];
    const float* W3a = (const float*)d_in[11];
    const float* b3a = (const float*)d_in[12];
    const float* W3b = (const float*)d_in[13];
    const float* b3b = (const float*)d_in[14];
    const float* Wc  = (const float*)d_in[15];
    const float* bc  = (const float*)d_in[16];

    int N = in_sizes[0] / 3;
    int F = in_sizes[2] / 3;

    float* ws   = (float*)d_ws;
    float* posn = ws;
    float* W1aT = posn + (size_t)N * 3;
    float* W2aT = W1aT + 6 * 32;
    float* W3aT = W2aT + 35 * 32;
    float* h1   = W3aT + 35 * 64;
    float* h2   = h1 + (size_t)N * 32;
    float* h3   = h2 + (size_t)N * 32;
    float* g    = h3 + (size_t)N * 64;
    int* deg    = (int*)(g + 64 * 64);       // doubles as fill cursor
    int* indptr = deg + N;
    int* srcids = indptr + (N + 1);

    hipMemsetAsync(deg, 0, (size_t)N * sizeof(int), stream);
    hipMemsetAsync(g, 0, 64 * 64 * sizeof(float), stream);

    prep_kernel<<<(N + 255) / 256, 256, 0, stream>>>(
        pos, posn, N, W1a, W2a, W3a, W1aT, W2aT, W3aT);

    int F3 = 3 * F;
    count_kernel<<<(F3 + 255) / 256, 256, 0, stream>>>(face, F3, deg);
    scan_kernel<<<1, 1024, 0, stream>>>(deg, indptr, N);
    fill_kernel<<<(F3 + 255) / 256, 256, 0, stream>>>(face, F, deg, srcids);

    dim3 blk(256);
    dim3 grd(((size_t)N * 4 + 255) / 256);
    layer_node_kernel<3, 32, 4, 4><<<grd, blk, 0, stream>>>(
        posn, posn, indptr, srcids, W1aT, b1a, W1b, b1b, h1, N);
    layer_node_kernel<32, 32, 4, 4><<<grd, blk, 0, stream>>>(
        h1, posn, indptr, srcids, W2aT, b2a, W2b, b2b, h2, N);
    layer_node_kernel<32, 64, 4, 2><<<grd, blk, 0, stream>>>(
        h2, posn, indptr, srcids, W3aT, b3a, W3b, b3b, h3, N);

    pool_kernel<<<(N + 1023) / 1024, 256, 0, stream>>>(h3, batch, N, g);
    head_kernel<<<(64 * 41 + 255) / 256, 256, 0, stream>>>(g, Wc, bc, (float*)d_out);
}